// Round 6
// baseline (161.878 us; speedup 1.0000x reference)
//
#include <hip/hip_runtime.h>
#include <math.h>

#define NS2 0.70710678118654752440f  // 1/sqrt(2)
#define NS3 0.57735026918962576451f  // 1/sqrt(3)
#define NS6 0.40824829046386301636f  // 1/sqrt(6)

typedef _Float16 half8 __attribute__((ext_vector_type(8)));

// ws layout (float offsets)
// W2 (fp16): [352 iterations][64 lanes] rows of 8 halves (16 B) — iteration-ordered
//   it 0..63    P1: c = it*64+l            v=b0[l], u=a0[it]
//   it 64..159  P4: s=it-64,m=s>>5,a=s&31  v=b0[l], u=A1[a]*d_m
//   it 160..351 b32 (ah=l>>5, bh=l&31), it2=it-160:
//     it2 0..15    P2: a=it2*2+ah            v=B1[bh], u=A1[a]*NS3dd
//     it2 16..111  P3: m=(it2-16)>>5, a=((it2-16)&31)*2+ah   u=a0[a]*d_m
//     it2 112..191 P5: m=(it2-112)>>4, a=((it2-112)&15)*2+ah u=A1[a]*q_m
#define OFF_W2   0        // fp16 region: 22528 rows * 16 B = 360448 B = 90112 floats
#define OFF_FEAT 180224   // [N/8 groups][208 rows][8]: a0 0-63, b0 64-127, A1 128-159, B1 160-191, geom 192-200
#define FEAT_STRIDE 1664

// prep: blocks 0..87 build W2 (fp16); blocks 88.. build per-group features + bias-init out
__global__ __launch_bounds__(256) void prep_kernel(
    const float* __restrict__ pos,
    const float* __restrict__ W1_0, const float* __restrict__ W1_1,
    const float* __restrict__ W2_0, const float* __restrict__ W2_1,
    const float* __restrict__ W3_0, const float* __restrict__ W3_1,
    const float* __restrict__ W3_2, const float* __restrict__ Wout,
    const float* __restrict__ bout,
    float* __restrict__ ws, float* __restrict__ out, int N)
{
    __shared__ float s_wo[1680];
    __shared__ float s_f0[8][64];
    __shared__ float s_f1[8][32];
    const int tid = threadIdx.x;

    if (blockIdx.x < 88) {
        for (int i = tid; i < 1680; i += 256) s_wo[i] = Wout[i];
        __syncthreads();
        int R = blockIdx.x * 256 + tid;          // 0..22527
        int it = R >> 6, l = R & 63;
        float acc[7] = {0.f,0.f,0.f,0.f,0.f,0.f,0.f};
        if (it < 64) {                            // P1
            const float* wr = W3_0 + (it*64 + l) * 64;
            #pragma unroll 4
            for (int o = 0; o < 64; o += 4) {
                float4 wv = *(const float4*)(wr + o);
                const float* w0 = s_wo + o * 7;
                #pragma unroll
                for (int k = 0; k < 7; ++k)
                    acc[k] = fmaf(wv.x, w0[k], fmaf(wv.y, w0[7+k],
                             fmaf(wv.z, w0[14+k], fmaf(wv.w, w0[21+k], acc[k]))));
            }
        } else if (it < 160) {                    // P4
            int s = it - 64, m = s >> 5, a = s & 31;
            const float* wr = W3_1 + (2048 + a*64 + l) * 32;
            #pragma unroll 4
            for (int o = 0; o < 32; o += 4) {
                float4 wv = *(const float4*)(wr + o);
                const float* w0 = s_wo + (64 + o*3 + m) * 7;
                #pragma unroll
                for (int k = 0; k < 7; ++k)
                    acc[k] = fmaf(wv.x, w0[k], fmaf(wv.y, w0[21+k],
                             fmaf(wv.z, w0[42+k], fmaf(wv.w, w0[63+k], acc[k]))));
            }
        } else {
            int it2 = it - 160, ah = l >> 5, bh = l & 31;
            if (it2 < 16) {                       // P2
                int a = it2*2 + ah;
                const float* wr = W3_0 + (4096 + a*32 + bh) * 64;
                #pragma unroll 4
                for (int o = 0; o < 64; o += 4) {
                    float4 wv = *(const float4*)(wr + o);
                    const float* w0 = s_wo + o * 7;
                    #pragma unroll
                    for (int k = 0; k < 7; ++k)
                        acc[k] = fmaf(wv.x, w0[k], fmaf(wv.y, w0[7+k],
                                 fmaf(wv.z, w0[14+k], fmaf(wv.w, w0[21+k], acc[k]))));
                }
            } else if (it2 < 112) {               // P3
                int u2 = it2 - 16, m = u2 >> 5, a = (u2 & 31)*2 + ah;
                const float* wr = W3_1 + (a*32 + bh) * 32;
                #pragma unroll 4
                for (int o = 0; o < 32; o += 4) {
                    float4 wv = *(const float4*)(wr + o);
                    const float* w0 = s_wo + (64 + o*3 + m) * 7;
                    #pragma unroll
                    for (int k = 0; k < 7; ++k)
                        acc[k] = fmaf(wv.x, w0[k], fmaf(wv.y, w0[21+k],
                                 fmaf(wv.z, w0[42+k], fmaf(wv.w, w0[63+k], acc[k]))));
                }
            } else {                              // P5
                int u2 = it2 - 112, m = u2 >> 4, a = (u2 & 15)*2 + ah;
                const float* wr = W3_2 + (a*32 + bh) * 16;
                #pragma unroll 4
                for (int o = 0; o < 16; o += 4) {
                    float4 wv = *(const float4*)(wr + o);
                    const float* w0 = s_wo + (160 + o*5 + m) * 7;
                    #pragma unroll
                    for (int k = 0; k < 7; ++k)
                        acc[k] = fmaf(wv.x, w0[k], fmaf(wv.y, w0[35+k],
                                 fmaf(wv.z, w0[70+k], fmaf(wv.w, w0[105+k], acc[k]))));
                }
            }
        }
        half8 h;
        #pragma unroll
        for (int k = 0; k < 7; ++k) h[k] = (_Float16)acc[k];
        h[7] = (_Float16)0.f;
        *(half8*)((char*)ws + (size_t)R * 16) = h;
        return;
    }

    // ---------------- feature build ----------------
    const int g    = blockIdx.x - 88;
    const int base = g * 8;
    float* feat = ws + OFF_FEAT + (size_t)g * FEAT_STRIDE;
    {
        int d = tid & 63;
        #pragma unroll
        for (int jj = 0; jj < 2; ++jj) {
            int j = (tid >> 6) + jj * 4;
            int n = base + j;
            float px = pos[n*3+0], py = pos[n*3+1], pz = pos[n*3+2];
            float r  = sqrtf(px*px + py*py + pz*pz) + 1e-9f;
            float t0 = r - (5.0f/63.0f) * (float)d;
            s_f0[j][d] = __expf(-4.f * t0 * t0);
        }
        {
            int j = tid >> 5, d1 = tid & 31;
            int n = base + j;
            float px = pos[n*3+0], py = pos[n*3+1], pz = pos[n*3+2];
            float r  = sqrtf(px*px + py*py + pz*pz) + 1e-9f;
            float t1 = r - (5.0f/31.0f) * (float)d1;
            s_f1[j][d1] = __expf(-4.f * t1 * t1);
        }
        if (tid < 8) {
            int n = base + tid;
            float px = pos[n*3+0], py = pos[n*3+1], pz = pos[n*3+2];
            float r  = sqrtf(px*px + py*py + pz*pz) + 1e-9f;
            float iv = 1.0f / r;
            float d0 = py*iv, d1 = pz*iv, d2 = px*iv;       // (y,z,x)
            feat[(192+0)*8 + tid] = d0;
            feat[(192+1)*8 + tid] = d1;
            feat[(192+2)*8 + tid] = d2;
            feat[(192+3)*8 + tid] = NS3 * (d0*d0 + d1*d1 + d2*d2);
            feat[(192+4)*8 + tid] = 2.f*NS2*d2*d0;
            feat[(192+5)*8 + tid] = 2.f*NS2*d0*d1;
            feat[(192+6)*8 + tid] = NS6*(2.f*d1*d1 - d2*d2 - d0*d0);
            feat[(192+7)*8 + tid] = 2.f*NS2*d2*d1;
            feat[(192+8)*8 + tid] = NS2*(d2*d2 - d0*d0);
        }
        if (tid < 56) out[base*7 + tid] = bout[tid % 7];
    }
    __syncthreads();
    {
        int c = tid & 63, jb = tid >> 6;
        float aa0 = 0.f, aa1 = 0.f, ba0 = 0.f, ba1 = 0.f;
        const float* wa = W1_0 + c;
        const float* wb = W2_0 + c;
        #pragma unroll 4
        for (int d = 0; d < 64; ++d) {
            float wav = wa[d*64], wbv = wb[d*64];
            float fA = s_f0[jb][d], fB = s_f0[jb+4][d];
            aa0 = fmaf(fA, wav, aa0);  aa1 = fmaf(fB, wav, aa1);
            ba0 = fmaf(fA, wbv, ba0);  ba1 = fmaf(fB, wbv, ba1);
        }
        feat[c*8 + jb]      = aa0;  feat[c*8 + jb + 4]      = aa1;
        feat[(64+c)*8 + jb] = ba0;  feat[(64+c)*8 + jb + 4] = ba1;

        int c1 = tid & 31, j8 = tid >> 5;
        float aA = 0.f, aB = 0.f;
        const float* wA = W1_1 + c1;
        const float* wB = W2_1 + c1;
        #pragma unroll 4
        for (int d = 0; d < 32; ++d) {
            float f = s_f1[j8][d];
            aA = fmaf(f, wA[d*32], aA);
            aB = fmaf(f, wB[d*32], aB);
        }
        feat[(128+c1)*8 + j8] = aA;
        feat[(160+c1)*8 + j8] = aB;
    }
}

// iteration -> weight-table row block; 16 streams, 10 A-iters + 12 B-iters each
__device__ __forceinline__ int it_of(int i, int s) {
    return (i < 10) ? (s*10 + i) : (160 + s*12 + (i - 10));
}

// grid = (N/8)*4; block (g, cs): 8 nodes, channel-streams cs*4+w per wave.
// NOTE: no min-waves clamp — R4's (256,4) forced VGPR=64 and spilled 144 MB to scratch.
__global__ __launch_bounds__(256) void main_kernel(
    const float* __restrict__ ws, float* __restrict__ out, int N)
{
    __shared__ __align__(16) float s_ug[544*8];    // iteration-ordered u*geom table
    __shared__ __align__(16) float s_A1[32*8];
    __shared__ __align__(16) float s_geom[9*8];
    __shared__ float s_red[4][56];

    const int tid  = threadIdx.x;
    const int w    = tid >> 6;
    const int lane = tid & 63;
    const int bh   = lane & 31, ah = lane >> 5;
    const int g    = blockIdx.x >> 2;
    const int cs   = blockIdx.x & 3;
    const int base = g * 8;
    const int stream = cs*4 + w;
    const float* feat = ws + OFF_FEAT + (size_t)g * FEAT_STRIDE;
    const half8* wp   = (const half8*)ws;          // fp16 weight rows, half8-indexed

    // ---- 8-deep prefetch ring prologue (pure global, before any barrier) ----
    half8 ring[8];
    #pragma unroll
    for (int s = 0; s < 8; ++s)
        ring[s] = wp[(size_t)it_of(s, stream)*64 + lane];

    // ---- stage features ----
    for (int i = tid; i < 128; i += 256) ((float4*)s_ug)[i]  = ((const float4*)feat)[i];   // a0 -> ug rows 0..63
    if (tid < 64) ((float4*)s_A1)[tid]  = ((const float4*)(feat + 128*8))[tid];            // A1
    if (tid < 18) ((float4*)s_geom)[tid] = ((const float4*)(feat + 192*8))[tid];           // geom
    float4 b0a = *(const float4*)(feat + (64+lane)*8);
    float4 b0b = *(const float4*)(feat + (64+lane)*8 + 4);
    float4 B1a = *(const float4*)(feat + (160+bh)*8);
    float4 B1b = *(const float4*)(feat + (160+bh)*8 + 4);
    float b0r[8] = {b0a.x,b0a.y,b0a.z,b0a.w,b0b.x,b0b.y,b0b.z,b0b.w};
    float B1r[8] = {B1a.x,B1a.y,B1a.z,B1a.w,B1b.x,B1b.y,B1b.z,B1b.w};
    __syncthreads();

    // ---- build ug rows 64..543, linear element indexing (conflict-free) ----
    // reads only s_ug rows <64, writes rows >=64: no race.
    for (int idx = tid; idx < 480*8; idx += 256) {
        int r = 64 + (idx >> 3), j = idx & 7;
        const float* u; const float* gs;
        if (r < 160) { int s = r - 64; u = s_A1 + (s & 31)*8; gs = s_geom + (s >> 5)*8; }
        else {
            int s = r - 160, it2 = s >> 1, half = s & 1;
            if (it2 < 16)       { int a = it2*2 + half;                                  u = s_A1 + a*8; gs = s_geom + 3*8; }
            else if (it2 < 112) { int u2 = it2-16;  int m = u2>>5; int a=(u2&31)*2+half; u = s_ug + a*8; gs = s_geom + m*8; }
            else                { int u2 = it2-112; int m = u2>>4; int a=(u2&15)*2+half; u = s_A1 + a*8; gs = s_geom + (4+m)*8; }
        }
        s_ug[r*8 + j] = u[j] * gs[j];
    }
    __syncthreads();

    float acc[8][7];
    #pragma unroll
    for (int j = 0; j < 8; ++j)
        #pragma unroll
        for (int k = 0; k < 7; ++k) acc[j][k] = 0.f;

    // ---- loop A: b64 iterations (P1, P4), v = b0[lane] ----
    const float* ugA = s_ug + stream*10*8;
    #pragma unroll
    for (int i = 0; i < 10; ++i) {
        half8 hv = ring[i & 7];
        if (i + 8 < 22)
            ring[i & 7] = wp[(size_t)it_of(i + 8, stream)*64 + lane];
        float gv[7];
        #pragma unroll
        for (int k = 0; k < 7; ++k) gv[k] = (float)hv[k];
        float4 u0 = *(const float4*)(ugA + i*8);
        float4 u1 = *(const float4*)(ugA + i*8 + 4);
        float uv[8] = {u0.x,u0.y,u0.z,u0.w,u1.x,u1.y,u1.z,u1.w};
        #pragma unroll
        for (int j = 0; j < 8; ++j) {
            float p = uv[j] * b0r[j];
            #pragma unroll
            for (int k = 0; k < 7; ++k) acc[j][k] = fmaf(p, gv[k], acc[j][k]);
        }
    }
    // ---- loop B: b32 iterations (P2, P3, P5), v = B1[bh], a-half = ah ----
    const float* ugB = s_ug + (160 + stream*24 + ah)*8;
    #pragma unroll
    for (int i = 10; i < 22; ++i) {
        half8 hv = ring[i & 7];
        if (i + 8 < 22)
            ring[i & 7] = wp[(size_t)it_of(i + 8, stream)*64 + lane];
        float gv[7];
        #pragma unroll
        for (int k = 0; k < 7; ++k) gv[k] = (float)hv[k];
        float4 u0 = *(const float4*)(ugB + (i-10)*16);
        float4 u1 = *(const float4*)(ugB + (i-10)*16 + 4);
        float uv[8] = {u0.x,u0.y,u0.z,u0.w,u1.x,u1.y,u1.z,u1.w};
        #pragma unroll
        for (int j = 0; j < 8; ++j) {
            float p = uv[j] * B1r[j];
            #pragma unroll
            for (int k = 0; k < 7; ++k) acc[j][k] = fmaf(p, gv[k], acc[j][k]);
        }
    }

    // ---- reduce 64 lanes -> 4 waves -> atomic ----
    #pragma unroll
    for (int j = 0; j < 8; ++j)
        #pragma unroll
        for (int k = 0; k < 7; ++k) {
            float v = acc[j][k];
            v += __shfl_xor(v, 1, 64);
            v += __shfl_xor(v, 2, 64);
            v += __shfl_xor(v, 4, 64);
            v += __shfl_xor(v, 8, 64);
            v += __shfl_xor(v, 16, 64);
            v += __shfl_xor(v, 32, 64);
            acc[j][k] = v;
        }
    if (lane == 0) {
        #pragma unroll
        for (int j = 0; j < 8; ++j)
            #pragma unroll
            for (int k = 0; k < 7; ++k)
                s_red[w][j*7 + k] = acc[j][k];
    }
    __syncthreads();
    if (tid < 56) {
        float v = s_red[0][tid] + s_red[1][tid] + s_red[2][tid] + s_red[3][tid];
        atomicAdd(&out[base*7 + tid], v);
    }
}

extern "C" void kernel_launch(void* const* d_in, const int* in_sizes, int n_in,
                              void* d_out, int out_size, void* d_ws, size_t ws_size,
                              hipStream_t stream)
{
    const float* pos  = (const float*)d_in[0];
    const float* W1_0 = (const float*)d_in[1];
    const float* W1_1 = (const float*)d_in[2];
    const float* W2_0 = (const float*)d_in[3];
    const float* W2_1 = (const float*)d_in[4];
    const float* W3_0 = (const float*)d_in[5];
    const float* W3_1 = (const float*)d_in[6];
    const float* W3_2 = (const float*)d_in[7];
    const float* Wout = (const float*)d_in[8];
    const float* bout = (const float*)d_in[9];
    float* ws  = (float*)d_ws;
    float* op  = (float*)d_out;
    int N = in_sizes[0] / 3;   // 4096
    int groups = N / 8;

    prep_kernel<<<88 + groups, 256, 0, stream>>>(pos, W1_0, W1_1, W2_0, W2_1,
                                                 W3_0, W3_1, W3_2, Wout, bout, ws, op, N);
    main_kernel<<<groups * 4, 256, 0, stream>>>(ws, op, N);
}

// Round 7
// 120.032 us; speedup vs baseline: 1.3486x; 1.3486x over previous
//
#include <hip/hip_runtime.h>
#include <math.h>

#define NS2 0.70710678118654752440f  // 1/sqrt(2)
#define NS3 0.57735026918962576451f  // 1/sqrt(3)
#define NS6 0.40824829046386301636f  // 1/sqrt(6)

typedef _Float16 half8 __attribute__((ext_vector_type(8)));

// ws layout (float offsets)
// [0]           W2 fp16: [352 it][64 lanes] rows of 8 halves (16 B) = 90112 floats
//   it 0..63    P1: v=b0[l], u=a0[it]
//   it 64..159  P4: s=it-64,m=s>>5,a=s&31  v=b0[l], u=A1[a]*d_m
//   it 160..351 b32 (ah=l>>5, bh=l&31), it2=it-160:
//     it2 0..15    P2: a=it2*2+ah, v=B1[bh], u=A1[a]*NS3dd
//     it2 16..111  P3: m=(it2-16)>>5, a=((it2-16)&31)*2+ah, u=a0[a]*d_m
//     it2 112..191 P5: m=(it2-112)>>4, a=((it2-112)&15)*2+ah, u=A1[a]*q_m
// [OFF_GRP]     per group g: [544 ug rows][8 nodes] fp32 (iteration-ordered, rows 160+ are
//               (it2,half) pairs) then [96 vb rows][8]: b0 0..63, B1 64..95
#define OFF_W2   0
#define OFF_GRP  90112
#define GRP_STRIDE 5120   // 4352 ug + 768 vb floats

// prep: blocks 0..87 build W2 (fp16); blocks 88.. build per-group ug/vb tables + bias-init out
__global__ __launch_bounds__(256) void prep_kernel(
    const float* __restrict__ pos,
    const float* __restrict__ W1_0, const float* __restrict__ W1_1,
    const float* __restrict__ W2_0, const float* __restrict__ W2_1,
    const float* __restrict__ W3_0, const float* __restrict__ W3_1,
    const float* __restrict__ W3_2, const float* __restrict__ Wout,
    const float* __restrict__ bout,
    float* __restrict__ ws, float* __restrict__ out, int N)
{
    __shared__ float smem[2464];
    const int tid = threadIdx.x;

    if (blockIdx.x < 88) {
        // ---------------- weight build (fp16 rows) ----------------
        float* s_wo = smem;                     // Wout 240x7
        for (int i = tid; i < 1680; i += 256) s_wo[i] = Wout[i];
        __syncthreads();
        int R = blockIdx.x * 256 + tid;         // 0..22527
        int it = R >> 6, l = R & 63;
        float acc[7] = {0.f,0.f,0.f,0.f,0.f,0.f,0.f};
        if (it < 64) {                            // P1
            const float* wr = W3_0 + (it*64 + l) * 64;
            #pragma unroll 4
            for (int o = 0; o < 64; o += 4) {
                float4 wv = *(const float4*)(wr + o);
                const float* w0 = s_wo + o * 7;
                #pragma unroll
                for (int k = 0; k < 7; ++k)
                    acc[k] = fmaf(wv.x, w0[k], fmaf(wv.y, w0[7+k],
                             fmaf(wv.z, w0[14+k], fmaf(wv.w, w0[21+k], acc[k]))));
            }
        } else if (it < 160) {                    // P4
            int s = it - 64, m = s >> 5, a = s & 31;
            const float* wr = W3_1 + (2048 + a*64 + l) * 32;
            #pragma unroll 4
            for (int o = 0; o < 32; o += 4) {
                float4 wv = *(const float4*)(wr + o);
                const float* w0 = s_wo + (64 + o*3 + m) * 7;
                #pragma unroll
                for (int k = 0; k < 7; ++k)
                    acc[k] = fmaf(wv.x, w0[k], fmaf(wv.y, w0[21+k],
                             fmaf(wv.z, w0[42+k], fmaf(wv.w, w0[63+k], acc[k]))));
            }
        } else {
            int it2 = it - 160, ah = l >> 5, bh = l & 31;
            if (it2 < 16) {                       // P2
                int a = it2*2 + ah;
                const float* wr = W3_0 + (4096 + a*32 + bh) * 64;
                #pragma unroll 4
                for (int o = 0; o < 64; o += 4) {
                    float4 wv = *(const float4*)(wr + o);
                    const float* w0 = s_wo + o * 7;
                    #pragma unroll
                    for (int k = 0; k < 7; ++k)
                        acc[k] = fmaf(wv.x, w0[k], fmaf(wv.y, w0[7+k],
                                 fmaf(wv.z, w0[14+k], fmaf(wv.w, w0[21+k], acc[k]))));
                }
            } else if (it2 < 112) {               // P3
                int u2 = it2 - 16, m = u2 >> 5, a = (u2 & 31)*2 + ah;
                const float* wr = W3_1 + (a*32 + bh) * 32;
                #pragma unroll 4
                for (int o = 0; o < 32; o += 4) {
                    float4 wv = *(const float4*)(wr + o);
                    const float* w0 = s_wo + (64 + o*3 + m) * 7;
                    #pragma unroll
                    for (int k = 0; k < 7; ++k)
                        acc[k] = fmaf(wv.x, w0[k], fmaf(wv.y, w0[21+k],
                                 fmaf(wv.z, w0[42+k], fmaf(wv.w, w0[63+k], acc[k]))));
                }
            } else {                              // P5
                int u2 = it2 - 112, m = u2 >> 4, a = (u2 & 15)*2 + ah;
                const float* wr = W3_2 + (a*32 + bh) * 16;
                #pragma unroll 4
                for (int o = 0; o < 16; o += 4) {
                    float4 wv = *(const float4*)(wr + o);
                    const float* w0 = s_wo + (160 + o*5 + m) * 7;
                    #pragma unroll
                    for (int k = 0; k < 7; ++k)
                        acc[k] = fmaf(wv.x, w0[k], fmaf(wv.y, w0[35+k],
                                 fmaf(wv.z, w0[70+k], fmaf(wv.w, w0[105+k], acc[k]))));
                }
            }
        }
        half8 h;
        #pragma unroll
        for (int k = 0; k < 7; ++k) h[k] = (_Float16)acc[k];
        h[7] = (_Float16)0.f;
        *(half8*)((char*)ws + (size_t)R * 16) = h;
        return;
    }

    // ---------------- per-group feature/ug build ----------------
    float* s_f0   = smem;          // [8][64]
    float* s_f1   = smem + 512;    // [8][32]
    float* s_a0   = smem + 768;    // [64][8]
    float* s_b0   = smem + 1280;   // [64][8]
    float* s_A1   = smem + 1792;   // [32][8]
    float* s_B1   = smem + 2048;   // [32][8]
    float* s_geom = smem + 2304;   // [9][8]

    const int g    = blockIdx.x - 88;
    const int base = g * 8;
    float* grp = ws + OFF_GRP + (size_t)g * GRP_STRIDE;
    {
        int d = tid & 63;
        #pragma unroll
        for (int jj = 0; jj < 2; ++jj) {
            int j = (tid >> 6) + jj * 4;
            int n = base + j;
            float px = pos[n*3+0], py = pos[n*3+1], pz = pos[n*3+2];
            float r  = sqrtf(px*px + py*py + pz*pz) + 1e-9f;
            float t0 = r - (5.0f/63.0f) * (float)d;
            s_f0[j*64 + d] = __expf(-4.f * t0 * t0);
        }
        {
            int j = tid >> 5, d1 = tid & 31;
            int n = base + j;
            float px = pos[n*3+0], py = pos[n*3+1], pz = pos[n*3+2];
            float r  = sqrtf(px*px + py*py + pz*pz) + 1e-9f;
            float t1 = r - (5.0f/31.0f) * (float)d1;
            s_f1[j*32 + d1] = __expf(-4.f * t1 * t1);
        }
        if (tid < 8) {
            int n = base + tid;
            float px = pos[n*3+0], py = pos[n*3+1], pz = pos[n*3+2];
            float r  = sqrtf(px*px + py*py + pz*pz) + 1e-9f;
            float iv = 1.0f / r;
            float d0 = py*iv, d1 = pz*iv, d2 = px*iv;       // (y,z,x)
            s_geom[0*8 + tid] = d0;
            s_geom[1*8 + tid] = d1;
            s_geom[2*8 + tid] = d2;
            s_geom[3*8 + tid] = NS3 * (d0*d0 + d1*d1 + d2*d2);
            s_geom[4*8 + tid] = 2.f*NS2*d2*d0;
            s_geom[5*8 + tid] = 2.f*NS2*d0*d1;
            s_geom[6*8 + tid] = NS6*(2.f*d1*d1 - d2*d2 - d0*d0);
            s_geom[7*8 + tid] = 2.f*NS2*d2*d1;
            s_geom[8*8 + tid] = NS2*(d2*d2 - d0*d0);
        }
        if (tid < 56) out[base*7 + tid] = bout[tid % 7];
    }
    __syncthreads();
    {
        int c = tid & 63, jb = tid >> 6;
        float aa0 = 0.f, aa1 = 0.f, ba0 = 0.f, ba1 = 0.f;
        const float* wa = W1_0 + c;
        const float* wb = W2_0 + c;
        #pragma unroll 4
        for (int d = 0; d < 64; ++d) {
            float wav = wa[d*64], wbv = wb[d*64];
            float fA = s_f0[jb*64 + d], fB = s_f0[(jb+4)*64 + d];
            aa0 = fmaf(fA, wav, aa0);  aa1 = fmaf(fB, wav, aa1);
            ba0 = fmaf(fA, wbv, ba0);  ba1 = fmaf(fB, wbv, ba1);
        }
        s_a0[c*8 + jb] = aa0;  s_a0[c*8 + jb + 4] = aa1;
        s_b0[c*8 + jb] = ba0;  s_b0[c*8 + jb + 4] = ba1;

        int c1 = tid & 31, j8 = tid >> 5;
        float aA = 0.f, aB = 0.f;
        const float* wA = W1_1 + c1;
        const float* wB = W2_1 + c1;
        #pragma unroll 4
        for (int d = 0; d < 32; ++d) {
            float f = s_f1[j8*32 + d];
            aA = fmaf(f, wA[d*32], aA);
            aB = fmaf(f, wB[d*32], aB);
        }
        s_A1[c1*8 + j8] = aA;
        s_B1[c1*8 + j8] = aB;
    }
    __syncthreads();
    // ug table [544][8] fp32 + vb [96][8], coalesced global writes
    for (int idx = tid; idx < 5120; idx += 256) {
        float val;
        if (idx < 4352) {
            int r = idx >> 3, j = idx & 7;
            if (r < 64) val = s_a0[r*8 + j];
            else if (r < 160) {
                int s = r - 64;
                val = s_A1[(s & 31)*8 + j] * s_geom[(s >> 5)*8 + j];
            } else {
                int s = r - 160, it2 = s >> 1, half = s & 1;
                if (it2 < 16)        val = s_A1[(it2*2 + half)*8 + j] * s_geom[3*8 + j];
                else if (it2 < 112) { int u2 = it2-16;  val = s_a0[((u2&31)*2 + half)*8 + j] * s_geom[(u2>>5)*8 + j]; }
                else                { int u2 = it2-112; val = s_A1[((u2&15)*2 + half)*8 + j] * s_geom[(4 + (u2>>4))*8 + j]; }
            }
        } else {
            int v = idx - 4352, r = v >> 3, j = v & 7;
            val = (r < 64) ? s_b0[r*8 + j] : s_B1[(r-64)*8 + j];
        }
        grp[idx] = val;
    }
}

// iteration -> weight-table row block; 8 streams, 20 A-iters + 24 B-iters each
__device__ __forceinline__ int it_of(int i, int s) {
    return (i < 20) ? (s*20 + i) : (160 + s*24 + (i - 20));
}

// grid = (N/8)*2; block (g, cs): 8 nodes, channel-streams cs*4+w per wave.
__global__ __launch_bounds__(256) void main_kernel(
    const float* __restrict__ ws, float* __restrict__ out, int N)
{
    __shared__ __align__(16) float s_ug[544*8];    // 17408 B
    __shared__ float s_red[4][56];

    const int tid  = threadIdx.x;
    const int w    = tid >> 6;
    const int lane = tid & 63;
    const int bh   = lane & 31, ah = lane >> 5;
    const int g    = blockIdx.x >> 1;
    const int cs   = blockIdx.x & 1;
    const int base = g * 8;
    const int stream = cs*4 + w;
    const float* grp = ws + OFF_GRP + (size_t)g * GRP_STRIDE;
    const half8* wp  = (const half8*)ws;           // fp16 weight rows

    // ---- 4-deep prefetch ring prologue (pure global, before any barrier) ----
    half8 ring[4];
    #pragma unroll
    for (int s = 0; s < 4; ++s)
        ring[s] = wp[(size_t)it_of(s, stream)*64 + lane];

    // ---- stage ug table (pure coalesced float4 copy) + per-lane v regs ----
    for (int i = tid; i < 1088; i += 256) ((float4*)s_ug)[i] = ((const float4*)grp)[i];
    const float* vb = grp + 4352;
    float4 b0a = *(const float4*)(vb + lane*8);
    float4 b0b = *(const float4*)(vb + lane*8 + 4);
    float4 B1a = *(const float4*)(vb + (64+bh)*8);
    float4 B1b = *(const float4*)(vb + (64+bh)*8 + 4);
    float b0r[8] = {b0a.x,b0a.y,b0a.z,b0a.w,b0b.x,b0b.y,b0b.z,b0b.w};
    float B1r[8] = {B1a.x,B1a.y,B1a.z,B1a.w,B1b.x,B1b.y,B1b.z,B1b.w};
    __syncthreads();

    float acc[8][7];
    #pragma unroll
    for (int j = 0; j < 8; ++j)
        #pragma unroll
        for (int k = 0; k < 7; ++k) acc[j][k] = 0.f;

    // ---- loop A: b64 iterations (P1, P4), v = b0[lane] ----
    const float* ugA = s_ug + stream*20*8;
    #pragma unroll 4
    for (int i = 0; i < 20; ++i) {
        int s = i & 3;
        half8 hv = ring[s];
        ring[s] = wp[(size_t)it_of(i + 4, stream)*64 + lane];
        float gv[7];
        #pragma unroll
        for (int k = 0; k < 7; ++k) gv[k] = (float)hv[k];
        float4 u0 = *(const float4*)(ugA + i*8);
        float4 u1 = *(const float4*)(ugA + i*8 + 4);
        float uv[8] = {u0.x,u0.y,u0.z,u0.w,u1.x,u1.y,u1.z,u1.w};
        #pragma unroll
        for (int j = 0; j < 8; ++j) {
            float p = uv[j] * b0r[j];
            #pragma unroll
            for (int k = 0; k < 7; ++k) acc[j][k] = fmaf(p, gv[k], acc[j][k]);
        }
    }
    // ---- loop B: b32 iterations (P2, P3, P5), v = B1[bh], a-half = ah ----
    const float* ugB = s_ug + (160 + stream*48 + ah)*8;
    #pragma unroll 4
    for (int i = 20; i < 44; ++i) {
        int s = i & 3;
        half8 hv = ring[s];
        int inext = i + 4; if (inext > 43) inext = 43;
        ring[s] = wp[(size_t)it_of(inext, stream)*64 + lane];
        float gv[7];
        #pragma unroll
        for (int k = 0; k < 7; ++k) gv[k] = (float)hv[k];
        float4 u0 = *(const float4*)(ugB + (i-20)*16);
        float4 u1 = *(const float4*)(ugB + (i-20)*16 + 4);
        float uv[8] = {u0.x,u0.y,u0.z,u0.w,u1.x,u1.y,u1.z,u1.w};
        #pragma unroll
        for (int j = 0; j < 8; ++j) {
            float p = uv[j] * B1r[j];
            #pragma unroll
            for (int k = 0; k < 7; ++k) acc[j][k] = fmaf(p, gv[k], acc[j][k]);
        }
    }

    // ---- reduce 64 lanes -> 4 waves -> atomic ----
    #pragma unroll
    for (int j = 0; j < 8; ++j)
        #pragma unroll
        for (int k = 0; k < 7; ++k) {
            float v = acc[j][k];
            v += __shfl_xor(v, 1, 64);
            v += __shfl_xor(v, 2, 64);
            v += __shfl_xor(v, 4, 64);
            v += __shfl_xor(v, 8, 64);
            v += __shfl_xor(v, 16, 64);
            v += __shfl_xor(v, 32, 64);
            acc[j][k] = v;
        }
    if (lane == 0) {
        #pragma unroll
        for (int j = 0; j < 8; ++j)
            #pragma unroll
            for (int k = 0; k < 7; ++k)
                s_red[w][j*7 + k] = acc[j][k];
    }
    __syncthreads();
    if (tid < 56) {
        float v = s_red[0][tid] + s_red[1][tid] + s_red[2][tid] + s_red[3][tid];
        atomicAdd(&out[base*7 + tid], v);
    }
}

extern "C" void kernel_launch(void* const* d_in, const int* in_sizes, int n_in,
                              void* d_out, int out_size, void* d_ws, size_t ws_size,
                              hipStream_t stream)
{
    const float* pos  = (const float*)d_in[0];
    const float* W1_0 = (const float*)d_in[1];
    const float* W1_1 = (const float*)d_in[2];
    const float* W2_0 = (const float*)d_in[3];
    const float* W2_1 = (const float*)d_in[4];
    const float* W3_0 = (const float*)d_in[5];
    const float* W3_1 = (const float*)d_in[6];
    const float* W3_2 = (const float*)d_in[7];
    const float* Wout = (const float*)d_in[8];
    const float* bout = (const float*)d_in[9];
    float* ws  = (float*)d_ws;
    float* op  = (float*)d_out;
    int N = in_sizes[0] / 3;   // 4096
    int groups = N / 8;

    prep_kernel<<<88 + groups, 256, 0, stream>>>(pos, W1_0, W1_1, W2_0, W2_1,
                                                 W3_0, W3_1, W3_2, Wout, bout, ws, op, N);
    main_kernel<<<groups * 2, 256, 0, stream>>>(ws, op, N);
}

// Round 8
// 100.658 us; speedup vs baseline: 1.6082x; 1.1925x over previous
//
#include <hip/hip_runtime.h>
#include <math.h>

#define NS2 0.70710678118654752440f  // 1/sqrt(2)
#define NS3 0.57735026918962576451f  // 1/sqrt(3)
#define NS6 0.40824829046386301636f  // 1/sqrt(6)

typedef _Float16 f16;
typedef _Float16 f16x8 __attribute__((ext_vector_type(8)));
typedef float    f32x4 __attribute__((ext_vector_type(4)));

// ---------------------------------------------------------------------------
// r-space (K) layout, 22528 entries, chunks of 32 (704 chunks):
//   A-section k 0..10239 (chunks 0..319): it = k>>6, l = k&63, v = b0[l]
//     it<64   P1: u = a0[it]            (gidx 9 = 1.0)
//     it>=64  P4: s=it-64: u = A1[s&31] * d_{s>>5}
//   B-section k 10240..22527 (chunks 320..703): it2=(k-10240)>>5, l32=k&31, v=B1[l32]
//     it2<32   P2: u = A1[it2]   * NS3*|d|^2 (gidx 3)
//     it2<224  P3: t=it2-32:  u = a0[t&63]  * d_{t>>6}
//     else     P5: t=it2-224: u = A1[t&31]  * q_{t>>5}
//
// ws layout (f16 units):
//   [0]        G_T [16][22528] f16 (rows 7..15 zero)   = 360448 f16
//   [OFF_UV]   per node [216] f16: a0[0..63] A1[64..95] b0[96..159] B1[160..191]
//              geom[192..200] (dY,dZ,dX, NS3dd, qq0..4), 1.0 at [201]
//   [OFF_IDX]  704 x u16 chunk table: uidx | gidx<<8
// ---------------------------------------------------------------------------
#define GT_K    22528
#define UV_ROW  216
#define OFF_UV  360448
#define OFF_IDX 1245184

__global__ __launch_bounds__(256) void prep_kernel(
    const float* __restrict__ pos,
    const float* __restrict__ W1_0, const float* __restrict__ W1_1,
    const float* __restrict__ W2_0, const float* __restrict__ W2_1,
    const float* __restrict__ W3_0, const float* __restrict__ W3_1,
    const float* __restrict__ W3_2, const float* __restrict__ Wout,
    const float* __restrict__ bout,
    f16* __restrict__ wsh, float* __restrict__ out, int N)
{
    __shared__ float smem[2464];
    const int tid = threadIdx.x;

    if (blockIdx.x < 88) {
        // ---------------- G_T build (transposed, f16) ----------------
        float* s_wo = smem;
        for (int i = tid; i < 1680; i += 256) s_wo[i] = Wout[i];
        __syncthreads();
        int k = blockIdx.x * 256 + tid;            // 0..22527
        float acc[7] = {0.f,0.f,0.f,0.f,0.f,0.f,0.f};
        if (k < 4096) {                            // P1
            int a = k >> 6, b = k & 63;
            const float* wr = W3_0 + (a*64 + b) * 64;
            #pragma unroll 4
            for (int o = 0; o < 64; o += 4) {
                float4 wv = *(const float4*)(wr + o);
                const float* w0 = s_wo + o * 7;
                #pragma unroll
                for (int kk = 0; kk < 7; ++kk)
                    acc[kk] = fmaf(wv.x, w0[kk], fmaf(wv.y, w0[7+kk],
                              fmaf(wv.z, w0[14+kk], fmaf(wv.w, w0[21+kk], acc[kk]))));
            }
        } else if (k < 10240) {                    // P4
            int it = k >> 6, s = it - 64, m = s >> 5, a2 = s & 31, l = k & 63;
            const float* wr = W3_1 + (2048 + a2*64 + l) * 32;
            #pragma unroll 4
            for (int o = 0; o < 32; o += 4) {
                float4 wv = *(const float4*)(wr + o);
                const float* w0 = s_wo + (64 + o*3 + m) * 7;
                #pragma unroll
                for (int kk = 0; kk < 7; ++kk)
                    acc[kk] = fmaf(wv.x, w0[kk], fmaf(wv.y, w0[21+kk],
                              fmaf(wv.z, w0[42+kk], fmaf(wv.w, w0[63+kk], acc[kk]))));
            }
        } else {
            int it2 = (k - 10240) >> 5, l32 = k & 31;
            if (it2 < 32) {                        // P2
                const float* wr = W3_0 + (4096 + it2*32 + l32) * 64;
                #pragma unroll 4
                for (int o = 0; o < 64; o += 4) {
                    float4 wv = *(const float4*)(wr + o);
                    const float* w0 = s_wo + o * 7;
                    #pragma unroll
                    for (int kk = 0; kk < 7; ++kk)
                        acc[kk] = fmaf(wv.x, w0[kk], fmaf(wv.y, w0[7+kk],
                                  fmaf(wv.z, w0[14+kk], fmaf(wv.w, w0[21+kk], acc[kk]))));
                }
            } else if (it2 < 224) {                // P3
                int t = it2 - 32, m = t >> 6, a = t & 63;
                const float* wr = W3_1 + (a*32 + l32) * 32;
                #pragma unroll 4
                for (int o = 0; o < 32; o += 4) {
                    float4 wv = *(const float4*)(wr + o);
                    const float* w0 = s_wo + (64 + o*3 + m) * 7;
                    #pragma unroll
                    for (int kk = 0; kk < 7; ++kk)
                        acc[kk] = fmaf(wv.x, w0[kk], fmaf(wv.y, w0[21+kk],
                                  fmaf(wv.z, w0[42+kk], fmaf(wv.w, w0[63+kk], acc[kk]))));
                }
            } else {                               // P5
                int t = it2 - 224, m = t >> 5, a = t & 31;
                const float* wr = W3_2 + (a*32 + l32) * 16;
                #pragma unroll 4
                for (int o = 0; o < 16; o += 4) {
                    float4 wv = *(const float4*)(wr + o);
                    const float* w0 = s_wo + (160 + o*5 + m) * 7;
                    #pragma unroll
                    for (int kk = 0; kk < 7; ++kk)
                        acc[kk] = fmaf(wv.x, w0[kk], fmaf(wv.y, w0[35+kk],
                                  fmaf(wv.z, w0[70+kk], fmaf(wv.w, w0[105+kk], acc[kk]))));
                }
            }
        }
        #pragma unroll
        for (int r = 0; r < 7; ++r)  wsh[(size_t)r * GT_K + k] = (f16)acc[r];
        #pragma unroll
        for (int r = 7; r < 16; ++r) wsh[(size_t)r * GT_K + k] = (f16)0.f;
        return;
    }

    if (blockIdx.x == 88 + 512) {
        // ---------------- chunk index table ----------------
        for (int c = tid; c < 704; c += 256) {
            int uidx, gidx;
            if (c < 320) {
                int it = c >> 1;
                if (it < 64) { uidx = it; gidx = 9; }
                else { int s = it - 64; uidx = 64 + (s & 31); gidx = s >> 5; }
            } else {
                int it2 = c - 320;
                if (it2 < 32)       { uidx = 64 + it2;                gidx = 3; }
                else if (it2 < 224) { int t = it2 - 32;  uidx = t & 63;       gidx = t >> 6; }
                else                { int t = it2 - 224; uidx = 64 + (t & 31); gidx = 4 + (t >> 5); }
            }
            ((unsigned short*)(wsh + OFF_IDX))[c] = (unsigned short)(uidx | (gidx << 8));
        }
        return;
    }

    // ---------------- per-node feature build (8 nodes/block) ----------------
    float* s_f0 = smem;          // [8][64]
    float* s_f1 = smem + 512;    // [8][32]
    const int g8   = blockIdx.x - 88;
    const int base = g8 * 8;
    f16* uv = wsh + OFF_UV;
    {
        int d = tid & 63;
        #pragma unroll
        for (int jj = 0; jj < 2; ++jj) {
            int j = (tid >> 6) + jj * 4;
            int n = base + j;
            float px = pos[n*3+0], py = pos[n*3+1], pz = pos[n*3+2];
            float r  = sqrtf(px*px + py*py + pz*pz) + 1e-9f;
            float t0 = r - (5.0f/63.0f) * (float)d;
            s_f0[j*64 + d] = __expf(-4.f * t0 * t0);
        }
        {
            int j = tid >> 5, d1 = tid & 31;
            int n = base + j;
            float px = pos[n*3+0], py = pos[n*3+1], pz = pos[n*3+2];
            float r  = sqrtf(px*px + py*py + pz*pz) + 1e-9f;
            float t1 = r - (5.0f/31.0f) * (float)d1;
            s_f1[j*32 + d1] = __expf(-4.f * t1 * t1);
        }
        if (tid < 8) {
            int n = base + tid;
            float px = pos[n*3+0], py = pos[n*3+1], pz = pos[n*3+2];
            float r  = sqrtf(px*px + py*py + pz*pz) + 1e-9f;
            float iv = 1.0f / r;
            float d0 = py*iv, d1 = pz*iv, d2 = px*iv;       // (y,z,x)
            f16* row = uv + (size_t)n * UV_ROW;
            row[192+0] = (f16)d0;
            row[192+1] = (f16)d1;
            row[192+2] = (f16)d2;
            row[192+3] = (f16)(NS3 * (d0*d0 + d1*d1 + d2*d2));
            row[192+4] = (f16)(2.f*NS2*d2*d0);
            row[192+5] = (f16)(2.f*NS2*d0*d1);
            row[192+6] = (f16)(NS6*(2.f*d1*d1 - d2*d2 - d0*d0));
            row[192+7] = (f16)(2.f*NS2*d2*d1);
            row[192+8] = (f16)(NS2*(d2*d2 - d0*d0));
            row[201]   = (f16)1.0f;
        }
        if (tid < 56) out[base*7 + tid] = bout[tid % 7];
    }
    __syncthreads();
    {
        int c = tid & 63, jb = tid >> 6;
        float aa0 = 0.f, aa1 = 0.f, ba0 = 0.f, ba1 = 0.f;
        const float* wa = W1_0 + c;
        const float* wb = W2_0 + c;
        #pragma unroll 4
        for (int d = 0; d < 64; ++d) {
            float wav = wa[d*64], wbv = wb[d*64];
            float fA = s_f0[jb*64 + d], fB = s_f0[(jb+4)*64 + d];
            aa0 = fmaf(fA, wav, aa0);  aa1 = fmaf(fB, wav, aa1);
            ba0 = fmaf(fA, wbv, ba0);  ba1 = fmaf(fB, wbv, ba1);
        }
        uv[(size_t)(base+jb  )*UV_ROW +      c] = (f16)aa0;
        uv[(size_t)(base+jb+4)*UV_ROW +      c] = (f16)aa1;
        uv[(size_t)(base+jb  )*UV_ROW + 96 + c] = (f16)ba0;
        uv[(size_t)(base+jb+4)*UV_ROW + 96 + c] = (f16)ba1;

        int c1 = tid & 31, j8 = tid >> 5;
        float aA = 0.f, aB = 0.f;
        const float* wA = W1_1 + c1;
        const float* wB = W2_1 + c1;
        #pragma unroll 4
        for (int d = 0; d < 32; ++d) {
            float f = s_f1[j8*32 + d];
            aA = fmaf(f, wA[d*32], aA);
            aB = fmaf(f, wB[d*32], aB);
        }
        uv[(size_t)(base+j8)*UV_ROW +  64 + c1] = (f16)aA;
        uv[(size_t)(base+j8)*UV_ROW + 160 + c1] = (f16)aB;
    }
}

// grid = 512: block (g = bi>>3 : 64-node group, kq = bi&7 : K-eighth).
// wave w handles node-tile nodes [g*64 + w*16, +16). D = G_T(16x K) x z(K x 16 nodes).
__global__ __launch_bounds__(256) void main_kernel(
    const f16* __restrict__ wsh, float* __restrict__ out, int N)
{
    __shared__ f16 s_g[2][16][264];        // G_T tile, 256 k + 8 pad per row
    __shared__ f16 s_uv[64][UV_ROW];       // per-node u/v/geom
    __shared__ f16 s_ugt[2][64][8];        // u*geom per (node, chunk-in-tile)
    __shared__ unsigned short s_idx[704];

    const int tid  = threadIdx.x;
    const int w    = tid >> 6;
    const int lane = tid & 63;
    const int lq   = lane >> 4;            // quad: A/B k-subrange, D row-group
    const int lm   = lane & 15;            // A row (out-k) / B col (node) / D col
    const int g    = blockIdx.x >> 3;
    const int kq   = blockIdx.x & 7;

    // ---- stage per-node table + idx table ----
    {
        const uint4* src = (const uint4*)(wsh + OFF_UV + (size_t)g * 64 * UV_ROW);
        uint4* dst = (uint4*)&s_uv[0][0];
        for (int j = tid; j < 1728; j += 256) dst[j] = src[j];
        const unsigned int* isrc = (const unsigned int*)(wsh + OFF_IDX);
        unsigned int* idst = (unsigned int*)s_idx;
        for (int j = tid; j < 352; j += 256) idst[j] = isrc[j];
    }
    __syncthreads();

    // ---- per-lane constant v-fragments ----
    const f16* myrow = &s_uv[w*16 + lm][0];
    f16x8 vA0 = *(const f16x8*)(myrow +  96 + lq*8);   // b0[ 0..31] slice
    f16x8 vA1 = *(const f16x8*)(myrow + 128 + lq*8);   // b0[32..63] slice
    f16x8 vB  = *(const f16x8*)(myrow + 160 + lq*8);   // B1[ 0..31] slice

    auto c0_of = [&](int t) {
        return (t < 5) ? (kq*40 + t*8) : (320 + kq*48 + (t-5)*8);
    };
    auto stage = [&](int t, int buf) {
        int c0 = c0_of(t), k0 = c0 * 32;
        const f16* src = wsh + k0;
        for (int j = tid; j < 512; j += 256) {          // 8 KB G tile
            int row = j >> 5, col = j & 31;
            uint4 v = *(const uint4*)(src + (size_t)row * GT_K + col*8);
            *(uint4*)&s_g[buf][row][col*8] = v;
        }
        for (int j = tid; j < 512; j += 256) {          // u*geom per (node, chunk)
            int n = j >> 3, s = j & 7;
            unsigned short ix = s_idx[c0 + s];
            float u  = (float)s_uv[n][ix & 255];
            float gg = (float)s_uv[n][192 + (ix >> 8)];
            s_ugt[buf][n][s] = (f16)(u * gg);
        }
    };

    f32x4 acc = {0.f, 0.f, 0.f, 0.f};
    auto compute = [&](int buf, bool isA) {
        #pragma unroll
        for (int s = 0; s < 8; ++s) {
            f16x8 a = *(const f16x8*)&s_g[buf][lm][s*32 + lq*8];
            f16 ug  = s_ugt[buf][w*16 + lm][s];
            f16x8 vv = isA ? ((s & 1) ? vA1 : vA0) : vB;
            f16x8 b;
            #pragma unroll
            for (int j2 = 0; j2 < 8; ++j2) b[j2] = vv[j2] * ug;
            acc = __builtin_amdgcn_mfma_f32_16x16x32_f16(a, b, acc, 0, 0, 0);
        }
    };

    stage(0, 0);
    __syncthreads();
    for (int t = 0; t < 11; ++t) {
        int buf = t & 1;
        if (t < 10) stage(t + 1, buf ^ 1);
        compute(buf, t < 5);
        __syncthreads();
    }

    // ---- epilogue: D col=lane&15 (node), row=lq*4+reg (out-k); rows 7..15 zero ----
    int node = g*64 + w*16 + lm;
    if (lq == 0) {
        #pragma unroll
        for (int r = 0; r < 4; ++r) atomicAdd(&out[node*7 + r], acc[r]);
    } else if (lq == 1) {
        #pragma unroll
        for (int r = 0; r < 3; ++r) atomicAdd(&out[node*7 + 4 + r], acc[r]);
    }
}

extern "C" void kernel_launch(void* const* d_in, const int* in_sizes, int n_in,
                              void* d_out, int out_size, void* d_ws, size_t ws_size,
                              hipStream_t stream)
{
    const float* pos  = (const float*)d_in[0];
    const float* W1_0 = (const float*)d_in[1];
    const float* W1_1 = (const float*)d_in[2];
    const float* W2_0 = (const float*)d_in[3];
    const float* W2_1 = (const float*)d_in[4];
    const float* W3_0 = (const float*)d_in[5];
    const float* W3_1 = (const float*)d_in[6];
    const float* W3_2 = (const float*)d_in[7];
    const float* Wout = (const float*)d_in[8];
    const float* bout = (const float*)d_in[9];
    f16*   wsh = (f16*)d_ws;
    float* op  = (float*)d_out;
    int N = in_sizes[0] / 3;   // 4096

    prep_kernel<<<88 + 512 + 1, 256, 0, stream>>>(pos, W1_0, W1_1, W2_0, W2_1,
                                                  W3_0, W3_1, W3_2, Wout, bout, wsh, op, N);
    main_kernel<<<512, 256, 0, stream>>>(wsh, op, N);
}

// Round 9
// 96.138 us; speedup vs baseline: 1.6838x; 1.0470x over previous
//
#include <hip/hip_runtime.h>
#include <math.h>

#define NS2 0.70710678118654752440f  // 1/sqrt(2)
#define NS3 0.57735026918962576451f  // 1/sqrt(3)
#define NS6 0.40824829046386301636f  // 1/sqrt(6)

typedef _Float16 f16;
typedef _Float16 f16x8 __attribute__((ext_vector_type(8)));
typedef float    f32x4 __attribute__((ext_vector_type(4)));

// ---------------------------------------------------------------------------
// r-space (K) layout, 22528 entries, chunks of 32 (704 chunks):
//   A-section k 0..10239 (chunks 0..319): it = k>>6, l = k&63, v = b0[l]
//     it<64   P1: u = a0[it]            (gidx 9 = 1.0)
//     it>=64  P4: s=it-64: u = A1[s&31] * d_{s>>5}
//   B-section k 10240..22527 (chunks 320..703): it2=(k-10240)>>5, l32=k&31, v=B1[l32]
//     it2<32   P2: u = A1[it2]   * NS3*|d|^2 (gidx 3)
//     it2<224  P3: t=it2-32:  u = a0[t&63]  * d_{t>>6}
//     else     P5: t=it2-224: u = A1[t&31]  * q_{t>>5}
//
// ws layout (f16 units):
//   [0]        G_T [7][22528] f16 (only the 7 real out-k rows; MFMA A-rows 7..15
//              are supplied as a zeroed LDS row in main)
//   [OFF_UV]   per node [216] f16: a0[0..63] A1[64..95] b0[96..159] B1[160..191]
//              geom[192..200] (dY,dZ,dX, NS3dd, qq0..4), 1.0 at [201]
// ---------------------------------------------------------------------------
#define GT_K    22528
#define UV_ROW  216
#define OFF_UV  157696   // 7*22528

// prep: blocks 0..351 build G_T (4 o-split threads per k, LDS reduce);
//       blocks 352.. build per-node features (8 nodes/block) + bias-init out
__global__ __launch_bounds__(256) void prep_kernel(
    const float* __restrict__ pos,
    const float* __restrict__ W1_0, const float* __restrict__ W1_1,
    const float* __restrict__ W2_0, const float* __restrict__ W2_1,
    const float* __restrict__ W3_0, const float* __restrict__ W3_1,
    const float* __restrict__ W3_2, const float* __restrict__ Wout,
    const float* __restrict__ bout,
    f16* __restrict__ wsh, float* __restrict__ out, int N)
{
    __shared__ float smem[3728];
    const int tid = threadIdx.x;

    if (blockIdx.x < 352) {
        // ---------------- G_T build: 64 k per block, 4 threads per k ----------------
        float* s_wo  = smem;            // Wout 240x7
        float* s_red = smem + 1680;     // [4][64][8] partials
        for (int i = tid; i < 1680; i += 256) s_wo[i] = Wout[i];
        __syncthreads();
        const int kl = tid & 63, q = tid >> 6;
        const int k  = blockIdx.x * 64 + kl;       // 0..22527
        float acc[7] = {0.f,0.f,0.f,0.f,0.f,0.f,0.f};
        if (k < 4096) {                            // P1  (L=64, quarter=16)
            const float* wr = W3_0 + (size_t)k * 64;
            #pragma unroll
            for (int oo = 0; oo < 16; oo += 4) {
                int o = q*16 + oo;
                float4 wv = *(const float4*)(wr + o);
                const float* w0 = s_wo + o * 7;
                #pragma unroll
                for (int kk = 0; kk < 7; ++kk)
                    acc[kk] = fmaf(wv.x, w0[kk], fmaf(wv.y, w0[7+kk],
                              fmaf(wv.z, w0[14+kk], fmaf(wv.w, w0[21+kk], acc[kk]))));
            }
        } else if (k < 10240) {                    // P4  (L=32, quarter=8)
            int it = k >> 6, s = it - 64, m = s >> 5, a2 = s & 31, l = k & 63;
            const float* wr = W3_1 + (size_t)(2048 + a2*64 + l) * 32;
            #pragma unroll
            for (int oo = 0; oo < 8; oo += 4) {
                int o = q*8 + oo;
                float4 wv = *(const float4*)(wr + o);
                const float* w0 = s_wo + (64 + o*3 + m) * 7;
                #pragma unroll
                for (int kk = 0; kk < 7; ++kk)
                    acc[kk] = fmaf(wv.x, w0[kk], fmaf(wv.y, w0[21+kk],
                              fmaf(wv.z, w0[42+kk], fmaf(wv.w, w0[63+kk], acc[kk]))));
            }
        } else {
            int it2 = (k - 10240) >> 5, l32 = k & 31;
            if (it2 < 32) {                        // P2  (L=64)
                const float* wr = W3_0 + (size_t)(4096 + it2*32 + l32) * 64;
                #pragma unroll
                for (int oo = 0; oo < 16; oo += 4) {
                    int o = q*16 + oo;
                    float4 wv = *(const float4*)(wr + o);
                    const float* w0 = s_wo + o * 7;
                    #pragma unroll
                    for (int kk = 0; kk < 7; ++kk)
                        acc[kk] = fmaf(wv.x, w0[kk], fmaf(wv.y, w0[7+kk],
                                  fmaf(wv.z, w0[14+kk], fmaf(wv.w, w0[21+kk], acc[kk]))));
                }
            } else if (it2 < 224) {                // P3  (L=32)
                int t = it2 - 32, m = t >> 6, a = t & 63;
                const float* wr = W3_1 + (size_t)(a*32 + l32) * 32;
                #pragma unroll
                for (int oo = 0; oo < 8; oo += 4) {
                    int o = q*8 + oo;
                    float4 wv = *(const float4*)(wr + o);
                    const float* w0 = s_wo + (64 + o*3 + m) * 7;
                    #pragma unroll
                    for (int kk = 0; kk < 7; ++kk)
                        acc[kk] = fmaf(wv.x, w0[kk], fmaf(wv.y, w0[21+kk],
                                  fmaf(wv.z, w0[42+kk], fmaf(wv.w, w0[63+kk], acc[kk]))));
                }
            } else {                               // P5  (L=16, quarter=4)
                int t = it2 - 224, m = t >> 5, a = t & 31;
                const float* wr = W3_2 + (size_t)(a*32 + l32) * 16;
                int o = q*4;
                float4 wv = *(const float4*)(wr + o);
                const float* w0 = s_wo + (160 + o*5 + m) * 7;
                #pragma unroll
                for (int kk = 0; kk < 7; ++kk)
                    acc[kk] = fmaf(wv.x, w0[kk], fmaf(wv.y, w0[35+kk],
                              fmaf(wv.z, w0[70+kk], fmaf(wv.w, w0[105+kk], acc[kk]))));
            }
        }
        #pragma unroll
        for (int r = 0; r < 7; ++r) s_red[(q*64 + kl)*8 + r] = acc[r];
        __syncthreads();
        if (tid < 64) {
            #pragma unroll
            for (int r = 0; r < 7; ++r) {
                float v = s_red[(      tid)*8 + r] + s_red[( 64 + tid)*8 + r]
                        + s_red[(128 + tid)*8 + r] + s_red[(192 + tid)*8 + r];
                wsh[(size_t)r * GT_K + blockIdx.x*64 + tid] = (f16)v;
            }
        }
        return;
    }

    // ---------------- per-node feature build (8 nodes/block) ----------------
    float* s_f0 = smem;          // [8][64]
    float* s_f1 = smem + 512;    // [8][32]
    const int g8   = blockIdx.x - 352;
    const int base = g8 * 8;
    f16* uv = wsh + OFF_UV;
    {
        int d = tid & 63;
        #pragma unroll
        for (int jj = 0; jj < 2; ++jj) {
            int j = (tid >> 6) + jj * 4;
            int n = base + j;
            float px = pos[n*3+0], py = pos[n*3+1], pz = pos[n*3+2];
            float r  = sqrtf(px*px + py*py + pz*pz) + 1e-9f;
            float t0 = r - (5.0f/63.0f) * (float)d;
            s_f0[j*64 + d] = __expf(-4.f * t0 * t0);
        }
        {
            int j = tid >> 5, d1 = tid & 31;
            int n = base + j;
            float px = pos[n*3+0], py = pos[n*3+1], pz = pos[n*3+2];
            float r  = sqrtf(px*px + py*py + pz*pz) + 1e-9f;
            float t1 = r - (5.0f/31.0f) * (float)d1;
            s_f1[j*32 + d1] = __expf(-4.f * t1 * t1);
        }
        if (tid < 8) {
            int n = base + tid;
            float px = pos[n*3+0], py = pos[n*3+1], pz = pos[n*3+2];
            float r  = sqrtf(px*px + py*py + pz*pz) + 1e-9f;
            float iv = 1.0f / r;
            float d0 = py*iv, d1 = pz*iv, d2 = px*iv;       // (y,z,x)
            f16* row = uv + (size_t)n * UV_ROW;
            row[192+0] = (f16)d0;
            row[192+1] = (f16)d1;
            row[192+2] = (f16)d2;
            row[192+3] = (f16)(NS3 * (d0*d0 + d1*d1 + d2*d2));
            row[192+4] = (f16)(2.f*NS2*d2*d0);
            row[192+5] = (f16)(2.f*NS2*d0*d1);
            row[192+6] = (f16)(NS6*(2.f*d1*d1 - d2*d2 - d0*d0));
            row[192+7] = (f16)(2.f*NS2*d2*d1);
            row[192+8] = (f16)(NS2*(d2*d2 - d0*d0));
            row[201]   = (f16)1.0f;
        }
        if (tid < 56) out[base*7 + tid] = bout[tid % 7];
    }
    __syncthreads();
    {
        int c = tid & 63, jb = tid >> 6;
        float aa0 = 0.f, aa1 = 0.f, ba0 = 0.f, ba1 = 0.f;
        const float* wa = W1_0 + c;
        const float* wb = W2_0 + c;
        #pragma unroll 4
        for (int d = 0; d < 64; ++d) {
            float wav = wa[d*64], wbv = wb[d*64];
            float fA = s_f0[jb*64 + d], fB = s_f0[(jb+4)*64 + d];
            aa0 = fmaf(fA, wav, aa0);  aa1 = fmaf(fB, wav, aa1);
            ba0 = fmaf(fA, wbv, ba0);  ba1 = fmaf(fB, wbv, ba1);
        }
        uv[(size_t)(base+jb  )*UV_ROW +      c] = (f16)aa0;
        uv[(size_t)(base+jb+4)*UV_ROW +      c] = (f16)aa1;
        uv[(size_t)(base+jb  )*UV_ROW + 96 + c] = (f16)ba0;
        uv[(size_t)(base+jb+4)*UV_ROW + 96 + c] = (f16)ba1;

        int c1 = tid & 31, j8 = tid >> 5;
        float aA = 0.f, aB = 0.f;
        const float* wA = W1_1 + c1;
        const float* wB = W2_1 + c1;
        #pragma unroll 4
        for (int d = 0; d < 32; ++d) {
            float f = s_f1[j8*32 + d];
            aA = fmaf(f, wA[d*32], aA);
            aB = fmaf(f, wB[d*32], aB);
        }
        uv[(size_t)(base+j8)*UV_ROW +  64 + c1] = (f16)aA;
        uv[(size_t)(base+j8)*UV_ROW + 160 + c1] = (f16)aB;
    }
}

// grid = 512: block (g = bi>>3 : 64-node group, kq = bi&7 : K-eighth).
// wave w handles nodes [g*64 + w*16, +16). D = G_T(16 x K) x z(K x 16 nodes);
// A rows 7..15 are a zeroed LDS row (lanes lm>=7 read row 7).
__global__ __launch_bounds__(256) void main_kernel(
    const f16* __restrict__ wsh, float* __restrict__ out, int N)
{
    __shared__ f16 s_g[2][8][264];         // G_T tile: 7 real rows + zero row 7
    __shared__ f16 s_uv[64][UV_ROW];       // per-node u/v/geom
    __shared__ f16 s_ugt[2][64][8];        // u*geom per (node, chunk-in-tile)
    __shared__ unsigned short s_idx[704];

    const int tid  = threadIdx.x;
    const int w    = tid >> 6;
    const int lane = tid & 63;
    const int lq   = lane >> 4;            // quad: A/B k-subrange, D row-group
    const int lm   = lane & 15;            // A row (out-k) / B col (node) / D col
    const int ra   = (lm < 7) ? lm : 7;    // A-source row (7 = zero row)
    const int g    = blockIdx.x >> 3;
    const int kq   = blockIdx.x & 7;

    // ---- stage per-node table; compute idx table; zero row 7 of both G bufs ----
    {
        const uint4* src = (const uint4*)(wsh + OFF_UV + (size_t)g * 64 * UV_ROW);
        uint4* dst = (uint4*)&s_uv[0][0];
        for (int j = tid; j < 1728; j += 256) dst[j] = src[j];
        for (int c = tid; c < 704; c += 256) {
            int uidx, gidx;
            if (c < 320) {
                int it = c >> 1;
                if (it < 64) { uidx = it; gidx = 9; }
                else { int s = it - 64; uidx = 64 + (s & 31); gidx = s >> 5; }
            } else {
                int it2 = c - 320;
                if (it2 < 32)       { uidx = 64 + it2;                 gidx = 3; }
                else if (it2 < 224) { int t = it2 - 32;  uidx = t & 63;        gidx = t >> 6; }
                else                { int t = it2 - 224; uidx = 64 + (t & 31); gidx = 4 + (t >> 5); }
            }
            s_idx[c] = (unsigned short)(uidx | (gidx << 8));
        }
        for (int i = tid; i < 264; i += 256) {
            s_g[0][7][i] = (f16)0.f;
            s_g[1][7][i] = (f16)0.f;
        }
    }
    __syncthreads();

    // ---- per-lane constant v-fragments ----
    const f16* myrow = &s_uv[w*16 + lm][0];
    f16x8 vA0 = *(const f16x8*)(myrow +  96 + lq*8);   // b0[ 0..31] slice
    f16x8 vA1 = *(const f16x8*)(myrow + 128 + lq*8);   // b0[32..63] slice
    f16x8 vB  = *(const f16x8*)(myrow + 160 + lq*8);   // B1[ 0..31] slice

    auto c0_of = [&](int t) {
        return (t < 5) ? (kq*40 + t*8) : (320 + kq*48 + (t-5)*8);
    };
    auto stage = [&](int t, int buf) {
        int c0 = c0_of(t), k0 = c0 * 32;
        const f16* src = wsh + k0;
        for (int j = tid; j < 224; j += 256) {          // 7 rows x 256 k (3.5 KB)
            int row = j >> 5, col = j & 31;
            uint4 v = *(const uint4*)(src + (size_t)row * GT_K + col*8);
            *(uint4*)&s_g[buf][row][col*8] = v;
        }
        for (int j = tid; j < 512; j += 256) {          // u*geom per (node, chunk)
            int n = j >> 3, s = j & 7;
            unsigned short ix = s_idx[c0 + s];
            float u  = (float)s_uv[n][ix & 255];
            float gg = (float)s_uv[n][192 + (ix >> 8)];
            s_ugt[buf][n][s] = (f16)(u * gg);
        }
    };

    f32x4 acc = {0.f, 0.f, 0.f, 0.f};
    auto compute = [&](int buf, bool isA) {
        #pragma unroll
        for (int s = 0; s < 8; ++s) {
            f16x8 a = *(const f16x8*)&s_g[buf][ra][s*32 + lq*8];
            f16 ug  = s_ugt[buf][w*16 + lm][s];
            f16x8 vv = isA ? ((s & 1) ? vA1 : vA0) : vB;
            f16x8 b;
            #pragma unroll
            for (int j2 = 0; j2 < 8; ++j2) b[j2] = vv[j2] * ug;
            acc = __builtin_amdgcn_mfma_f32_16x16x32_f16(a, b, acc, 0, 0, 0);
        }
    };

    stage(0, 0);
    __syncthreads();
    for (int t = 0; t < 11; ++t) {
        int buf = t & 1;
        if (t < 10) stage(t + 1, buf ^ 1);
        compute(buf, t < 5);
        __syncthreads();
    }

    // ---- epilogue: D col=lane&15 (node), row=lq*4+reg (out-k); rows 7..15 zero ----
    int node = g*64 + w*16 + lm;
    if (lq == 0) {
        #pragma unroll
        for (int r = 0; r < 4; ++r) atomicAdd(&out[node*7 + r], acc[r]);
    } else if (lq == 1) {
        #pragma unroll
        for (int r = 0; r < 3; ++r) atomicAdd(&out[node*7 + 4 + r], acc[r]);
    }
}

extern "C" void kernel_launch(void* const* d_in, const int* in_sizes, int n_in,
                              void* d_out, int out_size, void* d_ws, size_t ws_size,
                              hipStream_t stream)
{
    const float* pos  = (const float*)d_in[0];
    const float* W1_0 = (const float*)d_in[1];
    const float* W1_1 = (const float*)d_in[2];
    const float* W2_0 = (const float*)d_in[3];
    const float* W2_1 = (const float*)d_in[4];
    const float* W3_0 = (const float*)d_in[5];
    const float* W3_1 = (const float*)d_in[6];
    const float* W3_2 = (const float*)d_in[7];
    const float* Wout = (const float*)d_in[8];
    const float* bout = (const float*)d_in[9];
    f16*   wsh = (f16*)d_ws;
    float* op  = (float*)d_out;
    int N = in_sizes[0] / 3;   // 4096

    prep_kernel<<<352 + N/8, 256, 0, stream>>>(pos, W1_0, W1_1, W2_0, W2_1,
                                               W3_0, W3_1, W3_2, Wout, bout, wsh, op, N);
    main_kernel<<<512, 256, 0, stream>>>(wsh, op, N);
}